// Round 1
// baseline (368.376 us; speedup 1.0000x reference)
//
#include <hip/hip_runtime.h>
#include <cstdint>

// FCOS detection post-process for MI355X.
// Pipeline: score/box decode -> per-image exact top-1000 (bitonic chunk sort +
// merge) -> suppression bitmask -> sequential greedy NMS scan -> outputs.

typedef unsigned long long ull;

#define BATCH 16
#define NLOC 17064      // total FPN locations per image
#define NPAD 18432      // padded to 9 * 2048
#define NCHUNK 9
#define CHUNK 2048
#define TOPK 1000
#define TOPKP 1024
#define NCLS 80
#define SCORE_THR 0.05f
#define IOU_THR 0.6f

struct Ptrs { const float* cls[5]; const float* reg[5]; const float* ctr[5]; };

// ---------------------------------------------------------------- kernel 1 --
// One thread per (image, location): argmax over 80 class logits (sigmoid is
// monotonic), score = sqrt(sig(cls_max)*sig(ctr)), box decode, pack sort key.
// Key = (score_bits << 32) | (0xFFFFFFFF - n): descending sort == lax.top_k
// order (ties -> smaller index first). Padding locations get key 0.
__global__ __launch_bounds__(256) void score_kernel(Ptrs p, ull* __restrict__ keys,
                                                    int* __restrict__ labels,
                                                    float* __restrict__ boxes) {
  int idx = blockIdx.x * 256 + threadIdx.x;
  if (idx >= BATCH * NPAD) return;
  int b = idx / NPAD, n = idx - b * NPAD;
  if (n >= NLOC) { keys[idx] = 0ull; return; }

  int lvl, off, lw, st, H;
  if (n < 12800)      { lvl=0; off=0;     lw=7; st=8;   H=100; }
  else if (n < 16000) { lvl=1; off=12800; lw=6; st=16;  H=50;  }
  else if (n < 16800) { lvl=2; off=16000; lw=5; st=32;  H=25;  }
  else if (n < 17008) { lvl=3; off=16800; lw=4; st=64;  H=13;  }
  else                { lvl=4; off=17008; lw=3; st=128; H=7;   }
  int hw = n - off;
  int w = hw & ((1 << lw) - 1), h = hw >> lw;
  int HW = H << lw;
  float fs = (float)st, half = fs * 0.5f;
  float x = (float)w * fs + half, y = (float)h * fs + half;

  // coalesced across threads (consecutive hw) for each class c
  const float* cb = p.cls[lvl] + (size_t)b * NCLS * HW + hw;
  float best = cb[0]; int bi = 0;
  for (int c = 1; c < NCLS; ++c) {
    float v = cb[(size_t)c * HW];
    if (v > best) { best = v; bi = c; }   // strict > keeps first max (jnp.argmax)
  }
  const float* rb = p.reg[lvl] + (size_t)b * 4 * HW + hw;
  float r0 = rb[0], r1 = rb[HW], r2 = rb[2 * (size_t)HW], r3 = rb[3 * (size_t)HW];
  float ct = p.ctr[lvl][(size_t)b * HW + hw];

  float pcls = 1.f / (1.f + expf(-best));
  float pctr = 1.f / (1.f + expf(-ct));
  float score = sqrtf(pcls * pctr);   // (0,1), always positive -> monotonic bits

  keys[idx] = ((ull)__float_as_uint(score) << 32) | (ull)(0xFFFFFFFFu - (unsigned)n);
  labels[(size_t)b * NLOC + n] = bi + 1;
  float* bx = boxes + ((size_t)b * NLOC + n) * 4;
  bx[0] = x - r0; bx[1] = y - r1; bx[2] = x + r2; bx[3] = y + r3;
}

// ---------------------------------------------------------------- kernel 2 --
// Bitonic sort of one 2048 chunk in LDS (descending); emit top-1024.
__global__ __launch_bounds__(256) void chunk_sort_kernel(const ull* __restrict__ keys,
                                                         ull* __restrict__ runs) {
  __shared__ ull s[CHUNK];
  int b = blockIdx.x / NCHUNK, c = blockIdx.x % NCHUNK;
  const ull* src = keys + (size_t)b * NPAD + (size_t)c * CHUNK;
  for (int i = threadIdx.x; i < CHUNK; i += 256) s[i] = src[i];
  __syncthreads();
  for (int k = 2; k <= CHUNK; k <<= 1) {
    for (int j = k >> 1; j > 0; j >>= 1) {
      for (int t = threadIdx.x; t < CHUNK / 2; t += 256) {
        int i = ((t & ~(j - 1)) << 1) | (t & (j - 1));
        int ixj = i | j;
        bool desc = (i & k) == 0;
        ull a = s[i], bb = s[ixj];
        bool sw = desc ? (a < bb) : (a > bb);
        if (sw) { s[i] = bb; s[ixj] = a; }
      }
      __syncthreads();
    }
  }
  ull* dst = runs + ((size_t)b * NCHUNK + c) * TOPKP;
  for (int i = threadIdx.x; i < TOPKP; i += 256) dst[i] = s[i];
}

// ---------------------------------------------------------------- kernel 3 --
// Per image: fold 9 descending 1024-runs via bitonic merge, keeping top-1024.
// True top-1024 elements survive every merge => exact top-k, fully sorted.
__global__ __launch_bounds__(256) void merge_runs_kernel(const ull* __restrict__ runs,
                                                         ull* __restrict__ topkeys) {
  __shared__ ull m[2 * TOPKP];
  int b = blockIdx.x;
  const ull* rbase = runs + (size_t)b * NCHUNK * TOPKP;
  for (int i = threadIdx.x; i < TOPKP; i += 256) m[i] = rbase[i];
  for (int r = 1; r < NCHUNK; ++r) {
    __syncthreads();
    // append run r reversed -> bitonic sequence of 2048
    for (int i = threadIdx.x; i < TOPKP; i += 256)
      m[TOPKP + i] = rbase[(size_t)r * TOPKP + (TOPKP - 1 - i)];
    __syncthreads();
    for (int j = TOPKP; j > 0; j >>= 1) {
      for (int t = threadIdx.x; t < TOPKP; t += 256) {
        int i = ((t & ~(j - 1)) << 1) | (t & (j - 1));
        int ixj = i | j;
        ull a = m[i], bb = m[ixj];
        if (a < bb) { m[i] = bb; m[ixj] = a; }   // keep larger low -> descending
      }
      __syncthreads();
    }
  }
  for (int i = threadIdx.x; i < TOPKP; i += 256)
    topkeys[(size_t)b * TOPKP + i] = m[i];
}

// ---------------------------------------------------------------- kernel 4 --
// Decode keys, gather label/box, write output boxes, coord_max reduction
// (exact: max is order-independent), class-offset boxes, valid-bit words.
__global__ __launch_bounds__(256) void gather_kernel(const ull* __restrict__ topkeys,
    const int* __restrict__ labels, const float* __restrict__ boxes,
    float* __restrict__ topS, int* __restrict__ topL, float* __restrict__ topOB,
    ull* __restrict__ validWords, float* __restrict__ outBoxes) {
  __shared__ float red[256];
  __shared__ float s_cmax;
  int b = blockIdx.x, tid = threadIdx.x;
  float lmax = 0.f;   // reference maxes over where(valid, bx, 0) -> zeros included
  for (int k = tid; k < TOPKP; k += 256) {
    ull key = topkeys[(size_t)b * TOPKP + k];
    float sc = 0.f; int lb = 0;
    float b0 = 0.f, b1 = 0.f, b2 = 0.f, b3 = 0.f;
    bool inR = (k < TOPK);
    if (inR) {
      sc = __uint_as_float((unsigned)(key >> 32));
      unsigned n = 0xFFFFFFFFu - (unsigned)(key & 0xFFFFFFFFull);
      lb = labels[(size_t)b * NLOC + n];
      const float* bp = boxes + ((size_t)b * NLOC + n) * 4;
      b0 = bp[0]; b1 = bp[1]; b2 = bp[2]; b3 = bp[3];
      float* ob = outBoxes + ((size_t)b * TOPK + k) * 4;
      ob[0] = b0; ob[1] = b1; ob[2] = b2; ob[3] = b3;   // boxes output: all 1000
    }
    topS[(size_t)b * TOPKP + k] = sc;
    topL[(size_t)b * TOPKP + k] = lb;
    float* tb = topOB + ((size_t)b * TOPKP + k) * 4;
    tb[0] = b0; tb[1] = b1; tb[2] = b2; tb[3] = b3;
    bool valid = inR && (sc > SCORE_THR);
    if (valid) lmax = fmaxf(lmax, fmaxf(fmaxf(b0, b1), fmaxf(b2, b3)));
    ull vb = __ballot(valid ? 1 : 0);
    if ((tid & 63) == 0) validWords[b * 16 + (k >> 6)] = vb;
  }
  red[tid] = lmax;
  __syncthreads();
  for (int sft = 128; sft > 0; sft >>= 1) {
    if (tid < sft) red[tid] = fmaxf(red[tid], red[tid + sft]);
    __syncthreads();
  }
  if (tid == 0) s_cmax = red[0];
  __syncthreads();
  float offb = s_cmax + 1.0f;
  for (int k = tid; k < TOPKP; k += 256) {
    float off = (float)topL[(size_t)b * TOPKP + k] * offb;   // class-offset trick
    float* tb = topOB + ((size_t)b * TOPKP + k) * 4;
    tb[0] += off; tb[1] += off; tb[2] += off; tb[3] += off;
  }
}

// ---------------------------------------------------------------- kernel 5 --
// Suppression bitmask: block (b,i), thread j: bit = (j>i) & (iou(i,j) > thr).
// 16 uint64 words per row via per-wave ballot. FP op order mirrors reference.
__global__ __launch_bounds__(1024) void sup_kernel(const float* __restrict__ topOB,
                                                   ull* __restrict__ sup) {
  int bid = blockIdx.x;
  int b = bid / TOPK, i = bid - b * TOPK;
  int j = threadIdx.x;
  const float4* OB = (const float4*)topOB + (size_t)b * TOPKP;
  float4 A = OB[i];
  float aw = fmaxf(A.z - A.x, 0.f), ah = fmaxf(A.w - A.y, 0.f);
  float areaA = aw * ah;
  bool bit = false;
  if (j > i && j < TOPK) {
    float4 Bx = OB[j];
    float bw = fmaxf(Bx.z - Bx.x, 0.f), bh = fmaxf(Bx.w - Bx.y, 0.f);
    float areaB = bw * bh;
    float ix1 = fmaxf(A.x, Bx.x), iy1 = fmaxf(A.y, Bx.y);
    float ix2 = fminf(A.z, Bx.z), iy2 = fminf(A.w, Bx.w);
    float inter = fmaxf(ix2 - ix1, 0.f) * fmaxf(iy2 - iy1, 0.f);
    float uni = areaA + areaB - inter;
    float iou = inter / fmaxf(uni, 1e-9f);
    bit = iou > IOU_THR;
  }
  ull m = __ballot(bit ? 1 : 0);
  if ((j & 63) == 0) sup[(size_t)bid * 16 + (j >> 6)] = m;
}

// ---------------------------------------------------------------- kernel 6 --
// Greedy scan: 1 wave per image. Lanes 0..15 hold the 16 removed-bit words.
// Step i: shfl the owner word, test bit, OR suppression row if kept.
// Depth-8 row prefetch with STATIC register names (no runtime-indexed array).
__global__ __launch_bounds__(64) void nms_scan_kernel(const ull* __restrict__ sup,
    const ull* __restrict__ validWords, const float* __restrict__ topS,
    const int* __restrict__ topL, float* __restrict__ out) {
  int b = blockIdx.x, lane = threadIdx.x;
  bool act = lane < 16;
  ull removed = 0xFFFFFFFFFFFFFFFFull;
  if (act) removed = ~validWords[b * 16 + lane];   // keep starts as valid mask
  const ull* S = sup + (size_t)b * TOPK * 16;
  ull pre0 = act ? S[0 * 16 + lane] : 0ull;
  ull pre1 = act ? S[1 * 16 + lane] : 0ull;
  ull pre2 = act ? S[2 * 16 + lane] : 0ull;
  ull pre3 = act ? S[3 * 16 + lane] : 0ull;
  ull pre4 = act ? S[4 * 16 + lane] : 0ull;
  ull pre5 = act ? S[5 * 16 + lane] : 0ull;
  ull pre6 = act ? S[6 * 16 + lane] : 0ull;
  ull pre7 = act ? S[7 * 16 + lane] : 0ull;
  for (int base = 0; base < TOPK; base += 8) {   // 1000 = 125 * 8
#define STEP(u) { int i = base + u; ull row = pre##u; int nx = i + 8;          \
    pre##u = (act && nx < TOPK) ? S[(size_t)nx * 16 + lane] : 0ull;            \
    ull wv = __shfl(removed, i >> 6);                                          \
    if (!((wv >> (i & 63)) & 1ull)) removed |= row; }
    STEP(0) STEP(1) STEP(2) STEP(3) STEP(4) STEP(5) STEP(6) STEP(7)
#undef STEP
  }
  ull keepw = ~removed;
  const float* tS = topS + (size_t)b * TOPKP;
  const int*   tL = topL + (size_t)b * TOPKP;
  float* outS = out;                          // [16,1000]
  float* outL = out + BATCH * TOPK;           // [16,1000] labels as float
  float* outK = out + BATCH * TOPK * 6;       // after boxes block: 96000
  for (int t = 0; t < 16; ++t) {
    int j = t * 64 + lane;
    ull kw = __shfl(keepw, t);
    if (j < TOPK) {
      bool kp = (kw >> lane) & 1ull;
      outS[(size_t)b * TOPK + j] = kp ? tS[j] : 0.f;
      outL[(size_t)b * TOPK + j] = kp ? (float)tL[j] : 0.f;
      outK[(size_t)b * TOPK + j] = kp ? 1.f : 0.f;
    }
  }
}

// -------------------------------------------------------------------- host --
extern "C" void kernel_launch(void* const* d_in, const int* in_sizes, int n_in,
                              void* d_out, int out_size, void* d_ws, size_t ws_size,
                              hipStream_t stream) {
  Ptrs p;
  for (int l = 0; l < 5; ++l) {
    p.cls[l] = (const float*)d_in[l];
    p.reg[l] = (const float*)d_in[5 + l];
    p.ctr[l] = (const float*)d_in[10 + l];
  }
  char* ws = (char*)d_ws;
  size_t o = 0;
  auto alloc = [&](size_t bytes) -> void* {
    void* r = ws + o; o += (bytes + 255) & ~(size_t)255; return r;
  };
  ull*   keys       = (ull*)  alloc((size_t)BATCH * NPAD * 8);
  int*   labels     = (int*)  alloc((size_t)BATCH * NLOC * 4);
  float* boxes      = (float*)alloc((size_t)BATCH * NLOC * 16);
  ull*   runs       = (ull*)  alloc((size_t)BATCH * NCHUNK * TOPKP * 8);
  ull*   topkeys    = (ull*)  alloc((size_t)BATCH * TOPKP * 8);
  float* topS       = (float*)alloc((size_t)BATCH * TOPKP * 4);
  int*   topL       = (int*)  alloc((size_t)BATCH * TOPKP * 4);
  float* topOB      = (float*)alloc((size_t)BATCH * TOPKP * 16);
  ull*   validWords = (ull*)  alloc((size_t)BATCH * 16 * 8);
  ull*   sup        = (ull*)  alloc((size_t)BATCH * TOPK * 16 * 8);

  float* out = (float*)d_out;
  float* outBoxes = out + 2 * BATCH * TOPK;   // offset 32000

  hipLaunchKernelGGL(score_kernel, dim3((BATCH * NPAD + 255) / 256), dim3(256), 0, stream,
                     p, keys, labels, boxes);
  hipLaunchKernelGGL(chunk_sort_kernel, dim3(BATCH * NCHUNK), dim3(256), 0, stream,
                     keys, runs);
  hipLaunchKernelGGL(merge_runs_kernel, dim3(BATCH), dim3(256), 0, stream,
                     runs, topkeys);
  hipLaunchKernelGGL(gather_kernel, dim3(BATCH), dim3(256), 0, stream,
                     topkeys, labels, boxes, topS, topL, topOB, validWords, outBoxes);
  hipLaunchKernelGGL(sup_kernel, dim3(BATCH * TOPK), dim3(1024), 0, stream,
                     topOB, sup);
  hipLaunchKernelGGL(nms_scan_kernel, dim3(BATCH), dim3(64), 0, stream,
                     sup, validWords, topS, topL, out);
}